// Round 1
// baseline (156.717 us; speedup 1.0000x reference)
//
#include <hip/hip_runtime.h>

typedef __attribute__((ext_vector_type(8))) short bf16x8;
typedef __attribute__((ext_vector_type(4))) float f32x4;
typedef __attribute__((ext_vector_type(4))) int i32x4;
typedef __attribute__((ext_vector_type(2))) int i32x2;

#define DEV __device__ __forceinline__
#define WIN_ 1024

DEV short f2bf(float f) {
  union { float f; unsigned u; } a; a.f = f;
  unsigned r = a.u + 0x7fffu + ((a.u >> 16) & 1u);
  return (short)(r >> 16);
}
DEV float bf2f(short s) {
  union { unsigned u; float f; } a; a.u = ((unsigned)(unsigned short)s) << 16;
  return a.f;
}

// ---------------- bulk f32 -> bf16 ----------------
__global__ __launch_bounds__(256) void k_cvt(const float* __restrict__ src, short* __restrict__ dst, int n4) {
  int i = blockIdx.x * 256 + threadIdx.x;
  if (i >= n4) return;
  f32x4 v = *(const f32x4*)(src + (size_t)i * 4);
  i32x2 o;
  o[0] = (int)(((unsigned)(unsigned short)f2bf(v[0])) | (((unsigned)(unsigned short)f2bf(v[1])) << 16));
  o[1] = (int)(((unsigned)(unsigned short)f2bf(v[2])) | (((unsigned)(unsigned short)f2bf(v[3])) << 16));
  *(i32x2*)(dst + (size_t)i * 4) = o;
}

// ------- transpose f32 (K rows x N cols, ld=srcld) -> bf16 (N rows x 1024 cols) -------
__global__ __launch_bounds__(256) void k_transp(const float* __restrict__ src, short* __restrict__ dst, int srcld) {
  __shared__ float tile[32][33];
  int n0 = blockIdx.x * 32, k0 = blockIdx.y * 32;
  int tx = threadIdx.x, ty = threadIdx.y;
#pragma unroll
  for (int i = 0; i < 4; ++i)
    tile[ty * 4 + i][tx] = src[(size_t)(k0 + ty * 4 + i) * srcld + n0 + tx];
  __syncthreads();
#pragma unroll
  for (int i = 0; i < 4; ++i)
    dst[(size_t)(n0 + ty * 4 + i) * 1024 + k0 + tx] = f2bf(tile[tx][ty * 4 + i]);
}

// ---------------- bf16 GEMM: C = A(MxK) * BT(NxK)^T ----------------
// 128x128 tile, 4 waves (2x2), BK=32, mfma_f32_16x16x32_bf16
template <int LDC, bool F32OUT>
__global__ __launch_bounds__(256) void k_gemm_bt(const short* __restrict__ A, const short* __restrict__ BT,
                                                 void* __restrict__ Cv, int K) {
  __shared__ short As[128][40];
  __shared__ short Bs[128][40];
  const int tid = threadIdx.x;
  const int l = tid & 63, w = tid >> 6;
  const int l15 = l & 15, hi = l >> 4;
  const int wr = w >> 1, wc = w & 1;
  const int m0 = blockIdx.y * 128, n0 = blockIdx.x * 128;
  const int srow = tid >> 2, sseg = tid & 3;
  f32x4 acc[4][4];
#pragma unroll
  for (int i = 0; i < 4; ++i)
#pragma unroll
    for (int j = 0; j < 4; ++j) acc[i][j] = (f32x4){0.f, 0.f, 0.f, 0.f};

  for (int k0 = 0; k0 < K; k0 += 32) {
    __syncthreads();
#pragma unroll
    for (int it = 0; it < 2; ++it) {
      int row = srow + 64 * it;
      *(i32x4*)&As[row][sseg * 8] = *(const i32x4*)(A + (size_t)(m0 + row) * K + k0 + sseg * 8);
      *(i32x4*)&Bs[row][sseg * 8] = *(const i32x4*)(BT + (size_t)(n0 + row) * K + k0 + sseg * 8);
    }
    __syncthreads();
    bf16x8 af[4], bfr[4];
#pragma unroll
    for (int mi = 0; mi < 4; ++mi) af[mi] = *(const bf16x8*)&As[wr * 64 + 16 * mi + l15][8 * hi];
#pragma unroll
    for (int ni = 0; ni < 4; ++ni) bfr[ni] = *(const bf16x8*)&Bs[wc * 64 + 16 * ni + l15][8 * hi];
#pragma unroll
    for (int mi = 0; mi < 4; ++mi)
#pragma unroll
      for (int ni = 0; ni < 4; ++ni)
        acc[mi][ni] = __builtin_amdgcn_mfma_f32_16x16x32_bf16(af[mi], bfr[ni], acc[mi][ni], 0, 0, 0);
  }
#pragma unroll
  for (int mi = 0; mi < 4; ++mi)
#pragma unroll
    for (int ni = 0; ni < 4; ++ni)
#pragma unroll
      for (int r = 0; r < 4; ++r) {
        int row = m0 + wr * 64 + 16 * mi + 4 * hi + r;
        int col = n0 + wc * 64 + 16 * ni + l15;
        if (F32OUT) ((float*)Cv)[(size_t)row * LDC + col] = acc[mi][ni][r];
        else        ((short*)Cv)[(size_t)row * LDC + col] = f2bf(acc[mi][ni][r]);
      }
}

// ---------------- postproc: gate+ve add, RoPE, RMSNorm, relayout ----------------
// one thread per (hidx, b, t); hidx: 0..15 q-head, 16..19 k-head, 20..23 v-head
__global__ __launch_bounds__(256) void k_post(const short* __restrict__ qkv, const float* __restrict__ x,
    const float* __restrict__ ve, const float* __restrict__ cosp, const float* __restrict__ sinp,
    const float* __restrict__ Wg, short* __restrict__ qh, short* __restrict__ kh, short* __restrict__ vhT) {
  int g = blockIdx.x * 256 + threadIdx.x;
  int hidx = g >> 12;
  int bt = g & 4095;
  int b = bt >> 11, t = bt & 2047;
  const short* rowp = qkv + (size_t)bt * 1536;
  if (hidx < 20) {
    int col0 = (hidx < 16) ? hidx * 64 : 1024 + (hidx - 16) * 64;
    short vals[64];
#pragma unroll
    for (int s8 = 0; s8 < 8; ++s8) *(i32x4*)&vals[s8 * 8] = *(const i32x4*)(rowp + col0 + s8 * 8);
    const float* cp = cosp + (size_t)bt * 32;
    const float* sp = sinp + (size_t)bt * 32;
    float o[64]; float ss = 0.f;
#pragma unroll
    for (int j = 0; j < 32; ++j) {
      float a = bf2f(vals[j]), b2 = bf2f(vals[j + 32]);
      float c = cp[j], s = sp[j];
      float o1 = a * c + b2 * s;
      float o2 = b2 * c - a * s;
      o[j] = o1; o[j + 32] = o2;
      ss += o1 * o1 + o2 * o2;
    }
    float rinv = rsqrtf(ss * (1.f / 64.f) + 1e-6f);
    short* dst = (hidx < 16)
        ? qh + ((size_t)(b * 16 + hidx) * 2048 + t) * 64
        : kh + ((size_t)(b * 4 + (hidx - 16)) * 2048 + t) * 64;
#pragma unroll
    for (int s8 = 0; s8 < 8; ++s8) {
      i32x4 pk;
#pragma unroll
      for (int p = 0; p < 4; ++p) {
        int j = s8 * 8 + p * 2;
        pk[p] = (int)(((unsigned)(unsigned short)f2bf(o[j] * rinv)) |
                      (((unsigned)(unsigned short)f2bf(o[j + 1] * rinv)) << 16));
      }
      *(i32x4*)(dst + s8 * 8) = pk;
    }
  } else {
    int kvh = hidx - 20;
    const float* xr = x + (size_t)bt * 1024;
    float z = 0.f;
#pragma unroll
    for (int gg = 0; gg < 32; ++gg) z += xr[gg] * Wg[gg * 4 + kvh];
    float gate = 2.f / (1.f + __expf(-z));
    const float* vep = ve + (size_t)bt * 256 + kvh * 64;
    short vals[64];
#pragma unroll
    for (int s8 = 0; s8 < 8; ++s8)
      *(i32x4*)&vals[s8 * 8] = *(const i32x4*)(rowp + 1280 + kvh * 64 + s8 * 8);
    short* dst = vhT + (size_t)(b * 4 + kvh) * 64 * 2048 + t;
#pragma unroll
    for (int j = 0; j < 64; ++j) {
      float vv = bf2f(vals[j]) + gate * vep[j];
      dst[(size_t)j * 2048] = f2bf(vv);
    }
  }
}

// ---------------- flash attention, sliding-window causal, GQA ----------------
// block = (q-tile 64 rows) x head x batch; 4 waves, each wave 16 q-rows
__global__ __launch_bounds__(256) void k_attn(const short* __restrict__ qh, const short* __restrict__ kh,
                                              const short* __restrict__ vhT, short* __restrict__ yb) {
  __shared__ short Ks[64][72];      // [key][hd]
  __shared__ short Vt[64][72];      // [hd][key]
  __shared__ short Ps[4][16][72];   // per-wave P tile [qrow][key]
  const int qt = blockIdx.x, h = blockIdx.y, b = blockIdx.z;
  const int kvh = h >> 2;
  const int qs = qt * 64;
  const int tid = threadIdx.x;
  const int w = tid >> 6, l = tid & 63, l15 = l & 15, hi = l >> 4;

  const short* qb = qh + ((size_t)((b * 16 + h) * 2048 + qs + 16 * w + l15)) * 64;
  bf16x8 qf[2];
  qf[0] = *(const bf16x8*)(qb + 8 * hi);
  qf[1] = *(const bf16x8*)(qb + 32 + 8 * hi);

  f32x4 oacc[4];
#pragma unroll
  for (int i = 0; i < 4; ++i) oacc[i] = (f32x4){0.f, 0.f, 0.f, 0.f};
  float m[4], lsum[4];
#pragma unroll
  for (int r = 0; r < 4; ++r) { m[r] = -1e30f; lsum[r] = 0.f; }

  const int kt_lo = (qs >= 1024) ? ((qs - 1024) >> 6) : 0;
  const int kt_hi = qs >> 6;
  const short* kbase = kh + ((size_t)(b * 4 + kvh) * 2048) * 64;
  const short* vbase = vhT + ((size_t)(b * 4 + kvh) * 64) * 2048;

  for (int kt = kt_lo; kt <= kt_hi; ++kt) {
    __syncthreads();
#pragma unroll
    for (int it = 0; it < 2; ++it) {
      int idx = tid + 256 * it;
      int row = idx >> 3, seg = idx & 7;
      *(i32x4*)&Ks[row][seg * 8] = *(const i32x4*)(kbase + (size_t)(kt * 64 + row) * 64 + seg * 8);
      *(i32x4*)&Vt[row][seg * 8] = *(const i32x4*)(vbase + (size_t)row * 2048 + kt * 64 + seg * 8);
    }
    __syncthreads();

    f32x4 sacc[4];
#pragma unroll
    for (int nt = 0; nt < 4; ++nt) sacc[nt] = (f32x4){0.f, 0.f, 0.f, 0.f};
#pragma unroll
    for (int nt = 0; nt < 4; ++nt)
#pragma unroll
      for (int c = 0; c < 2; ++c) {
        bf16x8 kf = *(const bf16x8*)&Ks[16 * nt + l15][32 * c + 8 * hi];
        sacc[nt] = __builtin_amdgcn_mfma_f32_16x16x32_bf16(qf[c], kf, sacc[nt], 0, 0, 0);
      }

    const bool edge = (kt == kt_lo) || (kt == kt_hi);
#pragma unroll
    for (int r = 0; r < 4; ++r) {
      const int qi = qs + 16 * w + 4 * hi + r;
      float mx = -1e30f;
#pragma unroll
      for (int nt = 0; nt < 4; ++nt) {
        float s = sacc[nt][r] * 0.125f;
        if (edge) {
          int kj = kt * 64 + nt * 16 + l15;
          if (kj > qi || (qi - kj) > WIN_) s = -1e30f;
        }
        sacc[nt][r] = s;
        mx = fmaxf(mx, s);
      }
#pragma unroll
      for (int d = 1; d < 16; d <<= 1) mx = fmaxf(mx, __shfl_xor(mx, d));
      float mn = fmaxf(m[r], mx);
      float alpha = __expf(m[r] - mn);
      m[r] = mn;
      float rs = 0.f;
#pragma unroll
      for (int nt = 0; nt < 4; ++nt) {
        float p = __expf(sacc[nt][r] - mn);
        sacc[nt][r] = p;
        rs += p;
      }
#pragma unroll
      for (int d = 1; d < 16; d <<= 1) rs += __shfl_xor(rs, d);
      lsum[r] = lsum[r] * alpha + rs;
#pragma unroll
      for (int dt = 0; dt < 4; ++dt) oacc[dt][r] *= alpha;
#pragma unroll
      for (int nt = 0; nt < 4; ++nt) Ps[w][4 * hi + r][16 * nt + l15] = f2bf(sacc[nt][r]);
    }

    bf16x8 pa0 = *(const bf16x8*)&Ps[w][l15][8 * hi];
    bf16x8 pa1 = *(const bf16x8*)&Ps[w][l15][32 + 8 * hi];
#pragma unroll
    for (int dt = 0; dt < 4; ++dt) {
      bf16x8 vf0 = *(const bf16x8*)&Vt[16 * dt + l15][8 * hi];
      oacc[dt] = __builtin_amdgcn_mfma_f32_16x16x32_bf16(pa0, vf0, oacc[dt], 0, 0, 0);
      bf16x8 vf1 = *(const bf16x8*)&Vt[16 * dt + l15][32 + 8 * hi];
      oacc[dt] = __builtin_amdgcn_mfma_f32_16x16x32_bf16(pa1, vf1, oacc[dt], 0, 0, 0);
    }
  }

#pragma unroll
  for (int r = 0; r < 4; ++r) {
    float inv = 1.f / lsum[r];
    int row = b * 2048 + qs + 16 * w + 4 * hi + r;
#pragma unroll
    for (int dt = 0; dt < 4; ++dt)
      yb[(size_t)row * 1024 + h * 64 + dt * 16 + l15] = f2bf(oacc[dt][r] * inv);
  }
}

extern "C" void kernel_launch(void* const* d_in, const int* in_sizes, int n_in,
                              void* d_out, int out_size, void* d_ws, size_t ws_size,
                              hipStream_t stream) {
  const float* x    = (const float*)d_in[0];
  const float* ve   = (const float*)d_in[1];
  const float* cosp = (const float*)d_in[2];
  const float* sinp = (const float*)d_in[3];
  const float* Wq   = (const float*)d_in[4];
  const float* Wk   = (const float*)d_in[5];
  const float* Wv   = (const float*)d_in[6];
  const float* Wo   = (const float*)d_in[7];
  const float* Wg   = (const float*)d_in[8];
  float* out = (float*)d_out;

  char* ws = (char*)d_ws;
  short* xb   = (short*)(ws);                       // 4096x1024 bf16   (8,388,608 B)
  short* WbT  = (short*)(ws + 8388608);             // 1536x1024 bf16   (3,145,728 B)
  short* WoT  = (short*)(ws + 11534336);            // 1024x1024 bf16   (2,097,152 B)
  short* qkvb = (short*)(ws + 13631488);            // 4096x1536 bf16   (12,582,912 B)
  short* qh   = (short*)(ws + 26214400);            // (B,NH,T,HD) bf16 (8,388,608 B)
  short* kh   = (short*)(ws + 34603008);            // (B,NKV,T,HD)     (2,097,152 B)
  short* vhT  = (short*)(ws + 36700160);            // (B,NKV,HD,T)     (2,097,152 B)
  short* yb   = (short*)(ws + 38797312);            // 4096x1024 bf16   (8,388,608 B)

  // 1. x -> bf16
  k_cvt<<<4096, 256, 0, stream>>>(x, xb, 1048576);

  // 2. weights -> transposed bf16 (N x K layout, K=1024)
  dim3 tb(32, 8);
  k_transp<<<dim3(32, 32), tb, 0, stream>>>(Wq, WbT, 1024);
  k_transp<<<dim3(8, 32),  tb, 0, stream>>>(Wk, WbT + (size_t)1024 * 1024, 256);
  k_transp<<<dim3(8, 32),  tb, 0, stream>>>(Wv, WbT + (size_t)1280 * 1024, 256);
  k_transp<<<dim3(32, 32), tb, 0, stream>>>(Wo, WoT, 1024);

  // 3. qkv = x @ [Wq|Wk|Wv]  (4096 x 1536)
  k_gemm_bt<1536, false><<<dim3(12, 32), 256, 0, stream>>>(xb, WbT, qkvb, 1024);

  // 4. gate/ve add + rope + rmsnorm + relayout
  k_post<<<384, 256, 0, stream>>>(qkvb, x, ve, cosp, sinp, Wg, qh, kh, vhT);

  // 5. sliding-window causal attention
  k_attn<<<dim3(32, 16, 2), 256, 0, stream>>>(qh, kh, vhT, yb);

  // 6. out = y @ Wo  (f32)
  k_gemm_bt<1024, true><<<dim3(8, 32), 256, 0, stream>>>(yb, WoT, out, 1024);
}

// Round 3
// 138.270 us; speedup vs baseline: 1.1334x; 1.1334x over previous
//
#include <hip/hip_runtime.h>

typedef __attribute__((ext_vector_type(8))) short bf16x8;
typedef __attribute__((ext_vector_type(4))) short bf16x4;
typedef __attribute__((ext_vector_type(4))) float f32x4;
typedef __attribute__((ext_vector_type(4))) int i32x4;
typedef __attribute__((ext_vector_type(2))) int i32x2;

#define DEV __device__ __forceinline__
#define WIN_ 1024

DEV short f2bf(float f) {
  union { float f; unsigned u; } a; a.f = f;
  unsigned r = a.u + 0x7fffu + ((a.u >> 16) & 1u);
  return (short)(r >> 16);
}
DEV float bf2f(short s) {
  union { unsigned u; float f; } a; a.u = ((unsigned)(unsigned short)s) << 16;
  return a.f;
}
DEV unsigned pkbf2(float a, float b) {
  return ((unsigned)(unsigned short)f2bf(a)) | (((unsigned)(unsigned short)f2bf(b)) << 16);
}
DEV float fexp2(float x) {
#if __has_builtin(__builtin_amdgcn_exp2f)
  return __builtin_amdgcn_exp2f(x);
#else
  return exp2f(x);
#endif
}
DEV bf16x4 lohalf(bf16x8 v) { return __builtin_shufflevector(v, v, 0, 1, 2, 3); }
DEV bf16x4 hihalf(bf16x8 v) { return __builtin_shufflevector(v, v, 4, 5, 6, 7); }

DEV f32x4 mfma16(bf16x4 a, bf16x4 b, f32x4 c) {
#if __has_builtin(__builtin_amdgcn_mfma_f32_16x16x16bf16_1k)
  return __builtin_amdgcn_mfma_f32_16x16x16bf16_1k(a, b, c, 0, 0, 0);
#else
  asm volatile("s_nop 1\n\tv_mfma_f32_16x16x16_bf16 %0, %1, %2, %0\n\ts_nop 7\n\ts_nop 7"
               : "+v"(c) : "v"(a), "v"(b));
  return c;
#endif
}

// ---------------- bulk f32 -> bf16 ----------------
__global__ __launch_bounds__(256) void k_cvt(const float* __restrict__ src, short* __restrict__ dst, int n4) {
  int i = blockIdx.x * 256 + threadIdx.x;
  if (i >= n4) return;
  f32x4 v = *(const f32x4*)(src + (size_t)i * 4);
  i32x2 o;
  o[0] = (int)pkbf2(v[0], v[1]);
  o[1] = (int)pkbf2(v[2], v[3]);
  *(i32x2*)(dst + (size_t)i * 4) = o;
}

// ------- transpose f32 (K rows x N cols, ld=srcld) -> bf16 (N rows x 1024 cols) -------
__global__ __launch_bounds__(256) void k_transp(const float* __restrict__ src, short* __restrict__ dst, int srcld) {
  __shared__ float tile[32][33];
  int n0 = blockIdx.x * 32, k0 = blockIdx.y * 32;
  int tx = threadIdx.x, ty = threadIdx.y;
#pragma unroll
  for (int i = 0; i < 4; ++i)
    tile[ty * 4 + i][tx] = src[(size_t)(k0 + ty * 4 + i) * srcld + n0 + tx];
  __syncthreads();
#pragma unroll
  for (int i = 0; i < 4; ++i)
    dst[(size_t)(n0 + ty * 4 + i) * 1024 + k0 + tx] = f2bf(tile[tx][ty * 4 + i]);
}

// ---------------- bf16 GEMM: C = A(MxK) * BT(NxK)^T ----------------
template <int LDC, bool F32OUT>
__global__ __launch_bounds__(256) void k_gemm_bt(const short* __restrict__ A, const short* __restrict__ BT,
                                                 void* __restrict__ Cv, int K) {
  __shared__ short As[128][40];
  __shared__ short Bs[128][40];
  const int tid = threadIdx.x;
  const int l = tid & 63, w = tid >> 6;
  const int l15 = l & 15, hi = l >> 4;
  const int wr = w >> 1, wc = w & 1;
  const int m0 = blockIdx.y * 128, n0 = blockIdx.x * 128;
  const int srow = tid >> 2, sseg = tid & 3;
  f32x4 acc[4][4];
#pragma unroll
  for (int i = 0; i < 4; ++i)
#pragma unroll
    for (int j = 0; j < 4; ++j) acc[i][j] = (f32x4){0.f, 0.f, 0.f, 0.f};

  for (int k0 = 0; k0 < K; k0 += 32) {
    __syncthreads();
#pragma unroll
    for (int it = 0; it < 2; ++it) {
      int row = srow + 64 * it;
      *(i32x4*)&As[row][sseg * 8] = *(const i32x4*)(A + (size_t)(m0 + row) * K + k0 + sseg * 8);
      *(i32x4*)&Bs[row][sseg * 8] = *(const i32x4*)(BT + (size_t)(n0 + row) * K + k0 + sseg * 8);
    }
    __syncthreads();
    bf16x8 af[4], bfr[4];
#pragma unroll
    for (int mi = 0; mi < 4; ++mi) af[mi] = *(const bf16x8*)&As[wr * 64 + 16 * mi + l15][8 * hi];
#pragma unroll
    for (int ni = 0; ni < 4; ++ni) bfr[ni] = *(const bf16x8*)&Bs[wc * 64 + 16 * ni + l15][8 * hi];
#pragma unroll
    for (int mi = 0; mi < 4; ++mi)
#pragma unroll
      for (int ni = 0; ni < 4; ++ni)
        acc[mi][ni] = __builtin_amdgcn_mfma_f32_16x16x32_bf16(af[mi], bfr[ni], acc[mi][ni], 0, 0, 0);
  }
#pragma unroll
  for (int mi = 0; mi < 4; ++mi)
#pragma unroll
    for (int ni = 0; ni < 4; ++ni)
#pragma unroll
      for (int r = 0; r < 4; ++r) {
        int row = m0 + wr * 64 + 16 * mi + 4 * hi + r;
        int col = n0 + wc * 64 + 16 * ni + l15;
        if (F32OUT) ((float*)Cv)[(size_t)row * LDC + col] = acc[mi][ni][r];
        else        ((short*)Cv)[(size_t)row * LDC + col] = f2bf(acc[mi][ni][r]);
      }
}

// ---------------- postproc: gate+ve add, RoPE, RMSNorm, relayout ----------------
__global__ __launch_bounds__(256) void k_post(const short* __restrict__ qkv, const float* __restrict__ x,
    const float* __restrict__ ve, const float* __restrict__ cosp, const float* __restrict__ sinp,
    const float* __restrict__ Wg, short* __restrict__ qh, short* __restrict__ kh, short* __restrict__ vhT) {
  int g = blockIdx.x * 256 + threadIdx.x;
  int hidx = g >> 12;
  int bt = g & 4095;
  int b = bt >> 11, t = bt & 2047;
  const short* rowp = qkv + (size_t)bt * 1536;
  if (hidx < 20) {
    int col0 = (hidx < 16) ? hidx * 64 : 1024 + (hidx - 16) * 64;
    short vals[64];
#pragma unroll
    for (int s8 = 0; s8 < 8; ++s8) *(i32x4*)&vals[s8 * 8] = *(const i32x4*)(rowp + col0 + s8 * 8);
    const float* cp = cosp + (size_t)bt * 32;
    const float* sp = sinp + (size_t)bt * 32;
    float o[64]; float ss = 0.f;
#pragma unroll
    for (int j = 0; j < 32; ++j) {
      float a = bf2f(vals[j]), b2 = bf2f(vals[j + 32]);
      float c = cp[j], s = sp[j];
      float o1 = a * c + b2 * s;
      float o2 = b2 * c - a * s;
      o[j] = o1; o[j + 32] = o2;
      ss += o1 * o1 + o2 * o2;
    }
    float rinv = rsqrtf(ss * (1.f / 64.f) + 1e-6f);
    short* dst = (hidx < 16)
        ? qh + ((size_t)(b * 16 + hidx) * 2048 + t) * 64
        : kh + ((size_t)(b * 4 + (hidx - 16)) * 2048 + t) * 64;
#pragma unroll
    for (int s8 = 0; s8 < 8; ++s8) {
      i32x4 pk;
#pragma unroll
      for (int p = 0; p < 4; ++p) {
        int j = s8 * 8 + p * 2;
        pk[p] = (int)pkbf2(o[j] * rinv, o[j + 1] * rinv);
      }
      *(i32x4*)(dst + s8 * 8) = pk;
    }
  } else {
    int kvh = hidx - 20;
    const float* xr = x + (size_t)bt * 1024;
    float z = 0.f;
#pragma unroll
    for (int gg = 0; gg < 32; ++gg) z += xr[gg] * Wg[gg * 4 + kvh];
    float gate = 2.f / (1.f + __expf(-z));
    const float* vep = ve + (size_t)bt * 256 + kvh * 64;
    short vals[64];
#pragma unroll
    for (int s8 = 0; s8 < 8; ++s8)
      *(i32x4*)&vals[s8 * 8] = *(const i32x4*)(rowp + 1280 + kvh * 64 + s8 * 8);
    short* dst = vhT + (size_t)(b * 4 + kvh) * 64 * 2048 + t;
#pragma unroll
    for (int j = 0; j < 64; ++j) {
      float vv = bf2f(vals[j]) + gate * vep[j];
      dst[(size_t)j * 2048] = f2bf(vv);
    }
  }
}

// ---------------- flash attention, sliding-window causal, GQA ----------------
// block = (q-tile 64 rows) x head x batch; 4 waves, each wave 16 q-rows.
// Swapped QK^T (lane owns q=l15), PV via 16x16x16 MFMA (zero P round-trip),
// XOR-swizzled double-buffered K/V LDS, 1 barrier/tile, async staging.
__global__ __launch_bounds__(256) void k_attn(const short* __restrict__ qh, const short* __restrict__ kh,
                                              const short* __restrict__ vhT, short* __restrict__ yb) {
  __shared__ i32x4 lds4[2][1024];   // [buf][ K 8KB | V 8KB ]
  char* base = (char*)lds4;
  const int qt = blockIdx.x, h = blockIdx.y, b = blockIdx.z;
  const int kvh = h >> 2;
  const int qs = qt * 64;
  const int tid = threadIdx.x;
  const int w = tid >> 6, l = tid & 63, l15 = l & 15, hi = l >> 4;
  const int qi = qs + 16 * w + l15;          // this lane's softmax row
  const int rsw = (l15 & 7) << 4;

  const short* qb = qh + ((size_t)((b * 16 + h) * 2048 + qs + 16 * w + l15)) * 64;
  // B-frag wants d = 32c + 8hi + j -> select by hi
  bf16x8 qf0 = *(const bf16x8*)(qb + 8 * hi);
  bf16x8 qf1 = *(const bf16x8*)(qb + 32 + 8 * hi);

  f32x4 oacc[4];
#pragma unroll
  for (int i = 0; i < 4; ++i) oacc[i] = (f32x4){0.f, 0.f, 0.f, 0.f};
  float mrow = -1e30f, lsum = 0.f;

  const int kt_lo = (qs >= 1024) ? ((qs - 1024) >> 6) : 0;
  const int kt_hi = qs >> 6;
  const short* kbase = kh + ((size_t)(b * 4 + kvh) * 2048) * 64;
  const short* vbase = vhT + ((size_t)(b * 4 + kvh) * 64) * 2048;

  const int srow = tid >> 3, sseg = tid & 7;
  const int swz = (srow & 7) << 4;
  const int c20 = (sseg >> 1) * 8 + (sseg & 1) * 64;   // c2-permuted byte base for V
  i32x4 rk0, rk1, rv0, rv1;

#define LOADT(KT) do { \
    const short* kp = kbase + (size_t)((KT) * 64 + srow) * 64 + sseg * 8; \
    rk0 = *(const i32x4*)kp; \
    rk1 = *(const i32x4*)(kp + 32 * 64); \
    const short* vp = vbase + (size_t)srow * 2048 + (KT) * 64 + sseg * 8; \
    rv0 = *(const i32x4*)vp; \
    rv1 = *(const i32x4*)(vp + 32 * 2048); \
  } while (0)

#define WRITET(DST) do { \
    char* kd = (DST); \
    *(i32x4*)(kd + (((srow << 7) + (sseg << 4)) ^ swz)) = rk0; \
    *(i32x4*)(kd + ((((srow + 32) << 7) + (sseg << 4)) ^ swz)) = rk1; \
    char* vd = (DST) + 8192; \
    *(i32x2*)(vd + (((srow << 7) + c20) ^ swz)) = (i32x2){rv0[0], rv0[1]}; \
    *(i32x2*)(vd + (((srow << 7) + c20 + 32) ^ swz)) = (i32x2){rv0[2], rv0[3]}; \
    *(i32x2*)(vd + ((((srow + 32) << 7) + c20) ^ swz)) = (i32x2){rv1[0], rv1[1]}; \
    *(i32x2*)(vd + ((((srow + 32) << 7) + c20 + 32) ^ swz)) = (i32x2){rv1[2], rv1[3]}; \
  } while (0)

  LOADT(kt_lo);
  WRITET(base);
  __syncthreads();

  const float SC = 0.125f * 1.4426950408889634f;   // scale * log2(e)
  int cur = 0;

  for (int kt = kt_lo; kt <= kt_hi; ++kt) {
    if (kt < kt_hi) LOADT(kt + 1);
    char* kbuf = base + cur * 16384;
    char* vbuf = kbuf + 8192;

    // ---- QK^T swapped: s[nt] = K-tile(16 keys) x Q(16 q) ----
    f32x4 s[4];
#pragma unroll
    for (int nt = 0; nt < 4; ++nt) s[nt] = (f32x4){0.f, 0.f, 0.f, 0.f};
#pragma unroll
    for (int c = 0; c < 2; ++c) {
      bf16x8 qc = c ? qf1 : qf0;
#pragma unroll
      for (int nt = 0; nt < 4; ++nt) {
        bf16x8 kf = *(const bf16x8*)(kbuf + ((((16 * nt + l15) << 7) + (c << 6) + (hi << 4)) ^ rsw));
        s[nt] = __builtin_amdgcn_mfma_f32_16x16x32_bf16(kf, qc, s[nt], 0, 0, 0);
      }
    }

    // ---- online softmax (lane owns q = qi, 16 keys = 16nt+4hi+r) ----
    const bool edge = (kt == kt_lo) || (kt == kt_hi);
    const int k0 = kt * 64;
    float pm = -1e30f;
#pragma unroll
    for (int nt = 0; nt < 4; ++nt)
#pragma unroll
      for (int r = 0; r < 4; ++r) {
        float t = s[nt][r] * SC;
        if (edge) {
          int kj = k0 + 16 * nt + 4 * hi + r;
          if (kj > qi || (qi - kj) > WIN_) t = -1e30f;
        }
        s[nt][r] = t;
        pm = fmaxf(pm, t);
      }
    pm = fmaxf(pm, __shfl_xor(pm, 16));
    pm = fmaxf(pm, __shfl_xor(pm, 32));

    if (__ballot(pm > mrow + 12.f)) {            // defer-max rescale
      float mnew = fmaxf(mrow, pm);
      float alpha = fexp2(mrow - mnew);
      mrow = mnew;
      lsum *= alpha;
      float a0 = __shfl(alpha, 20 * hi + 0);
      float a1 = __shfl(alpha, 20 * hi + 1);
      float a2 = __shfl(alpha, 20 * hi + 2);
      float a3 = __shfl(alpha, 20 * hi + 3);
#pragma unroll
      for (int dt = 0; dt < 4; ++dt) {
        oacc[dt][0] *= a0; oacc[dt][1] *= a1; oacc[dt][2] *= a2; oacc[dt][3] *= a3;
      }
    }

    float rs = 0.f;
#pragma unroll
    for (int nt = 0; nt < 4; ++nt)
#pragma unroll
      for (int r = 0; r < 4; ++r) {
        float p = fexp2(s[nt][r] - mrow);
        s[nt][r] = p;
        rs += p;
      }
    rs += __shfl_xor(rs, 16);
    rs += __shfl_xor(rs, 32);
    lsum += rs;

    // ---- pack P into 16x16x16 A-frags (k = 4hi+r matches register layout) ----
    bf16x4 pa[4];
#pragma unroll
    for (int nt = 0; nt < 4; ++nt) {
      i32x2 pk = {(int)pkbf2(s[nt][0], s[nt][1]), (int)pkbf2(s[nt][2], s[nt][3])};
      pa[nt] = __builtin_bit_cast(bf16x4, pk);
    }

    // ---- PV: oacc[dt] += sum_nt P(:,nt) * V(nt, dt) ----
#pragma unroll
    for (int dt = 0; dt < 4; ++dt) {
      int rowb = ((16 * dt + l15) << 7) + (hi << 5);
      bf16x8 vv0 = *(const bf16x8*)(vbuf + (rowb ^ rsw));
      bf16x8 vv1 = *(const bf16x8*)(vbuf + ((rowb + 16) ^ rsw));
      oacc[dt] = mfma16(pa[0], lohalf(vv0), oacc[dt]);
      oacc[dt] = mfma16(pa[1], hihalf(vv0), oacc[dt]);
      oacc[dt] = mfma16(pa[2], lohalf(vv1), oacc[dt]);
      oacc[dt] = mfma16(pa[3], hihalf(vv1), oacc[dt]);
    }

    if (kt < kt_hi) WRITET(base + (cur ^ 1) * 16384);
    __syncthreads();
    cur ^= 1;
  }
#undef LOADT
#undef WRITET

  // ---- epilogue: normalize by lsum[q=4hi+r] and store ----
  float l0 = __shfl(lsum, 20 * hi + 0);
  float l1 = __shfl(lsum, 20 * hi + 1);
  float l2 = __shfl(lsum, 20 * hi + 2);
  float l3 = __shfl(lsum, 20 * hi + 3);
  float inv0 = 1.f / l0, inv1 = 1.f / l1, inv2 = 1.f / l2, inv3 = 1.f / l3;
#pragma unroll
  for (int dt = 0; dt < 4; ++dt) {
    size_t colb = (size_t)(h * 64 + 16 * dt + l15);
    size_t row0 = (size_t)(b * 2048 + qs + 16 * w + 4 * hi);
    yb[(row0 + 0) * 1024 + colb] = f2bf(oacc[dt][0] * inv0);
    yb[(row0 + 1) * 1024 + colb] = f2bf(oacc[dt][1] * inv1);
    yb[(row0 + 2) * 1024 + colb] = f2bf(oacc[dt][2] * inv2);
    yb[(row0 + 3) * 1024 + colb] = f2bf(oacc[dt][3] * inv3);
  }
}

extern "C" void kernel_launch(void* const* d_in, const int* in_sizes, int n_in,
                              void* d_out, int out_size, void* d_ws, size_t ws_size,
                              hipStream_t stream) {
  const float* x    = (const float*)d_in[0];
  const float* ve   = (const float*)d_in[1];
  const float* cosp = (const float*)d_in[2];
  const float* sinp = (const float*)d_in[3];
  const float* Wq   = (const float*)d_in[4];
  const float* Wk   = (const float*)d_in[5];
  const float* Wv   = (const float*)d_in[6];
  const float* Wo   = (const float*)d_in[7];
  const float* Wg   = (const float*)d_in[8];
  float* out = (float*)d_out;

  char* ws = (char*)d_ws;
  short* xb   = (short*)(ws);                       // 4096x1024 bf16
  short* WbT  = (short*)(ws + 8388608);             // 1536x1024 bf16
  short* WoT  = (short*)(ws + 11534336);            // 1024x1024 bf16
  short* qkvb = (short*)(ws + 13631488);            // 4096x1536 bf16
  short* qh   = (short*)(ws + 26214400);            // (B,NH,T,HD) bf16
  short* kh   = (short*)(ws + 34603008);            // (B,NKV,T,HD)
  short* vhT  = (short*)(ws + 36700160);            // (B,NKV,HD,T)
  short* yb   = (short*)(ws + 38797312);            // 4096x1024 bf16

  k_cvt<<<4096, 256, 0, stream>>>(x, xb, 1048576);

  dim3 tb(32, 8);
  k_transp<<<dim3(32, 32), tb, 0, stream>>>(Wq, WbT, 1024);
  k_transp<<<dim3(8, 32),  tb, 0, stream>>>(Wk, WbT + (size_t)1024 * 1024, 256);
  k_transp<<<dim3(8, 32),  tb, 0, stream>>>(Wv, WbT + (size_t)1280 * 1024, 256);
  k_transp<<<dim3(32, 32), tb, 0, stream>>>(Wo, WoT, 1024);

  k_gemm_bt<1536, false><<<dim3(12, 32), 256, 0, stream>>>(xb, WbT, qkvb, 1024);

  k_post<<<384, 256, 0, stream>>>(qkvb, x, ve, cosp, sinp, Wg, qh, kh, vhT);

  k_attn<<<dim3(32, 16, 2), 256, 0, stream>>>(qh, kh, vhT, yb);

  k_gemm_bt<1024, true><<<dim3(8, 32), 256, 0, stream>>>(yb, WoT, out, 1024);
}

// Round 4
// 125.030 us; speedup vs baseline: 1.2534x; 1.1059x over previous
//
#include <hip/hip_runtime.h>

typedef __attribute__((ext_vector_type(8))) short bf16x8;
typedef __attribute__((ext_vector_type(4))) short bf16x4;
typedef __attribute__((ext_vector_type(4))) float f32x4;
typedef __attribute__((ext_vector_type(4))) int i32x4;
typedef __attribute__((ext_vector_type(2))) int i32x2;

#define DEV __device__ __forceinline__
#define WIN_ 1024

DEV short f2bf(float f) {
  union { float f; unsigned u; } a; a.f = f;
  unsigned r = a.u + 0x7fffu + ((a.u >> 16) & 1u);
  return (short)(r >> 16);
}
DEV float bf2f(short s) {
  union { unsigned u; float f; } a; a.u = ((unsigned)(unsigned short)s) << 16;
  return a.f;
}
DEV unsigned pkbf2(float a, float b) {
  return ((unsigned)(unsigned short)f2bf(a)) | (((unsigned)(unsigned short)f2bf(b)) << 16);
}
DEV float fexp2(float x) {
#if __has_builtin(__builtin_amdgcn_exp2f)
  return __builtin_amdgcn_exp2f(x);
#else
  return exp2f(x);
#endif
}

DEV f32x4 mfma16(bf16x4 a, bf16x4 b, f32x4 c) {
#if __has_builtin(__builtin_amdgcn_mfma_f32_16x16x16bf16_1k)
  return __builtin_amdgcn_mfma_f32_16x16x16bf16_1k(a, b, c, 0, 0, 0);
#else
  asm volatile("s_nop 1\n\tv_mfma_f32_16x16x16_bf16 %0, %1, %2, %0\n\ts_nop 7\n\ts_nop 7"
               : "+v"(c) : "v"(a), "v"(b));
  return c;
#endif
}

DEV void gload16(const short* g, short* l) {
  __builtin_amdgcn_global_load_lds((const __attribute__((address_space(1))) unsigned int*)g,
                                   (__attribute__((address_space(3))) unsigned int*)l,
                                   16, 0, 0);
}

// ---------------- bulk f32 -> bf16 ----------------
__global__ __launch_bounds__(256) void k_cvt(const float* __restrict__ src, short* __restrict__ dst, int n4) {
  int i = blockIdx.x * 256 + threadIdx.x;
  if (i >= n4) return;
  f32x4 v = *(const f32x4*)(src + (size_t)i * 4);
  i32x2 o;
  o[0] = (int)pkbf2(v[0], v[1]);
  o[1] = (int)pkbf2(v[2], v[3]);
  *(i32x2*)(dst + (size_t)i * 4) = o;
}

// ------- transpose f32 (K rows x N cols, ld=srcld) -> bf16 (N rows x 1024 cols) -------
__global__ __launch_bounds__(256) void k_transp(const float* __restrict__ src, short* __restrict__ dst, int srcld) {
  __shared__ float tile[32][33];
  int n0 = blockIdx.x * 32, k0 = blockIdx.y * 32;
  int tx = threadIdx.x, ty = threadIdx.y;
#pragma unroll
  for (int i = 0; i < 4; ++i)
    tile[ty * 4 + i][tx] = src[(size_t)(k0 + ty * 4 + i) * srcld + n0 + tx];
  __syncthreads();
#pragma unroll
  for (int i = 0; i < 4; ++i)
    dst[(size_t)(n0 + ty * 4 + i) * 1024 + k0 + tx] = f2bf(tile[tx][ty * 4 + i]);
}

// ---------------- bf16 GEMM: C = A(MxK) * BT(NxK)^T ----------------
// 128x128 tile, 4 waves (2x2), BK=32, linear LDS + global_load_lds (m97 structure)
template <int LDC, bool F32OUT>
__global__ __launch_bounds__(256) void k_gemm_bt(const short* __restrict__ A, const short* __restrict__ BT,
                                                 void* __restrict__ Cv, int K) {
  __shared__ short As[128 * 32];
  __shared__ short Bs[128 * 32];
  const int tid = threadIdx.x;
  const int l = tid & 63, w = tid >> 6;
  const int l15 = l & 15, hi = l >> 4;
  const int wr = w >> 1, wc = w & 1;
  const int m0 = blockIdx.y * 128, n0 = blockIdx.x * 128;
  const int row = tid >> 2, seg8 = (tid & 3) * 8;
  short* lA = &As[tid * 8];
  short* lB = &Bs[tid * 8];
  const short* pa0 = A + (size_t)(m0 + row) * K + seg8;
  const short* pa1 = pa0 + (size_t)64 * K;
  const short* pb0 = BT + (size_t)(n0 + row) * K + seg8;
  const short* pb1 = pb0 + (size_t)64 * K;

  f32x4 acc[4][4];
#pragma unroll
  for (int i = 0; i < 4; ++i)
#pragma unroll
    for (int j = 0; j < 4; ++j) acc[i][j] = (f32x4){0.f, 0.f, 0.f, 0.f};

  for (int k0 = 0; k0 < K; k0 += 32) {
    __syncthreads();
    gload16(pa0 + k0, lA);
    gload16(pa1 + k0, lA + 2048);
    gload16(pb0 + k0, lB);
    gload16(pb1 + k0, lB + 2048);
    __syncthreads();
    bf16x8 af[4], bfr[4];
#pragma unroll
    for (int mi = 0; mi < 4; ++mi) af[mi] = *(const bf16x8*)&As[(wr * 64 + 16 * mi + l15) * 32 + 8 * hi];
#pragma unroll
    for (int ni = 0; ni < 4; ++ni) bfr[ni] = *(const bf16x8*)&Bs[(wc * 64 + 16 * ni + l15) * 32 + 8 * hi];
#pragma unroll
    for (int mi = 0; mi < 4; ++mi)
#pragma unroll
      for (int ni = 0; ni < 4; ++ni)
        acc[mi][ni] = __builtin_amdgcn_mfma_f32_16x16x32_bf16(af[mi], bfr[ni], acc[mi][ni], 0, 0, 0);
  }
#pragma unroll
  for (int mi = 0; mi < 4; ++mi)
#pragma unroll
    for (int ni = 0; ni < 4; ++ni)
#pragma unroll
      for (int r = 0; r < 4; ++r) {
        int crow = m0 + wr * 64 + 16 * mi + 4 * hi + r;
        int ccol = n0 + wc * 64 + 16 * ni + l15;
        if (F32OUT) ((float*)Cv)[(size_t)crow * LDC + ccol] = acc[mi][ni][r];
        else        ((short*)Cv)[(size_t)crow * LDC + ccol] = f2bf(acc[mi][ni][r]);
      }
}

// ---------------- postproc: gate+ve add, RoPE, RMSNorm, relayout ----------------
// q is additionally scaled by 0.125*log2(e) so attention works in exp2 domain.
__global__ __launch_bounds__(256) void k_post(const short* __restrict__ qkv, const float* __restrict__ x,
    const float* __restrict__ ve, const float* __restrict__ cosp, const float* __restrict__ sinp,
    const float* __restrict__ Wg, short* __restrict__ qh, short* __restrict__ kh, short* __restrict__ vhT) {
  int g = blockIdx.x * 256 + threadIdx.x;
  int hidx = g >> 12;
  int bt = g & 4095;
  int b = bt >> 11, t = bt & 2047;
  const short* rowp = qkv + (size_t)bt * 1536;
  if (hidx < 20) {
    int col0 = (hidx < 16) ? hidx * 64 : 1024 + (hidx - 16) * 64;
    short vals[64];
#pragma unroll
    for (int s8 = 0; s8 < 8; ++s8) *(i32x4*)&vals[s8 * 8] = *(const i32x4*)(rowp + col0 + s8 * 8);
    const float* cp = cosp + (size_t)bt * 32;
    const float* sp = sinp + (size_t)bt * 32;
    float o[64]; float ss = 0.f;
#pragma unroll
    for (int j = 0; j < 32; ++j) {
      float a = bf2f(vals[j]), b2 = bf2f(vals[j + 32]);
      float c = cp[j], s = sp[j];
      float o1 = a * c + b2 * s;
      float o2 = b2 * c - a * s;
      o[j] = o1; o[j + 32] = o2;
      ss += o1 * o1 + o2 * o2;
    }
    float rinv = rsqrtf(ss * (1.f / 64.f) + 1e-6f);
    if (hidx < 16) rinv *= 0.18033688011112042f;   // 0.125 * log2(e)
    short* dst = (hidx < 16)
        ? qh + ((size_t)(b * 16 + hidx) * 2048 + t) * 64
        : kh + ((size_t)(b * 4 + (hidx - 16)) * 2048 + t) * 64;
#pragma unroll
    for (int s8 = 0; s8 < 8; ++s8) {
      i32x4 pk;
#pragma unroll
      for (int p = 0; p < 4; ++p) {
        int j = s8 * 8 + p * 2;
        pk[p] = (int)pkbf2(o[j] * rinv, o[j + 1] * rinv);
      }
      *(i32x4*)(dst + s8 * 8) = pk;
    }
  } else {
    int kvh = hidx - 20;
    const float* xr = x + (size_t)bt * 1024;
    float z = 0.f;
#pragma unroll
    for (int gg = 0; gg < 32; ++gg) z += xr[gg] * Wg[gg * 4 + kvh];
    float gate = 2.f / (1.f + __expf(-z));
    const float* vep = ve + (size_t)bt * 256 + kvh * 64;
    short vals[64];
#pragma unroll
    for (int s8 = 0; s8 < 8; ++s8)
      *(i32x4*)&vals[s8 * 8] = *(const i32x4*)(rowp + 1280 + kvh * 64 + s8 * 8);
    short* dst = vhT + (size_t)(b * 4 + kvh) * 64 * 2048 + t;
#pragma unroll
    for (int j = 0; j < 64; ++j) {
      float vv = bf2f(vals[j]) + gate * vep[j];
      dst[(size_t)j * 2048] = f2bf(vv);
    }
  }
}

// ---------------- flash attention, sliding-window causal, GQA ----------------
// 1D grid, balanced qt decode (each CU-slot group of 4 blocks sums to 51 tiles).
// Swapped QK^T (lane owns q=l15); transposed PV (O^T = V * P^T) so softmax
// stats stay lane-local; K/V LDS identical row-major XOR-swizzled format.
__global__ __launch_bounds__(256) void k_attn(const short* __restrict__ qh, const short* __restrict__ kh,
                                              const short* __restrict__ vhT, short* __restrict__ yb) {
  __shared__ i32x4 lds4[2][1024];   // [buf][ K 8KB | V 8KB ]
  char* base = (char*)lds4;
  const int bid = blockIdx.x;
  const int kq = bid >> 8, low = bid & 255;
  const int h = low & 15, b = (low >> 4) & 1, q0 = low >> 5;
  const int qt = (kq == 0) ? (31 - q0) : (kq == 1) ? (16 + q0) : (kq == 2) ? (15 - q0) : q0;
  const int kvh = h >> 2;
  const int qs = qt * 64;
  const int tid = threadIdx.x;
  const int w = tid >> 6, l = tid & 63, l15 = l & 15, hi = l >> 4;
  const int qi = qs + 16 * w + l15;          // this lane's softmax row
  const int rsw = (l15 & 7) << 4;

  const short* qb = qh + ((size_t)((b * 16 + h) * 2048 + qs + 16 * w + l15)) * 64;
  bf16x8 qf0 = *(const bf16x8*)(qb + 8 * hi);
  bf16x8 qf1 = *(const bf16x8*)(qb + 32 + 8 * hi);

  f32x4 oacc[4];
#pragma unroll
  for (int i = 0; i < 4; ++i) oacc[i] = (f32x4){0.f, 0.f, 0.f, 0.f};
  float mrow = -1e30f, lsum = 0.f;

  const int kt_lo = (qs >= 1024) ? ((qs - 1024) >> 6) : 0;
  const int kt_hi = qs >> 6;
  const short* kbase = kh + ((size_t)(b * 4 + kvh) * 2048) * 64;
  const short* vbase = vhT + ((size_t)(b * 4 + kvh) * 64) * 2048;

  const int srow = tid >> 3, sseg = tid & 7;
  const int swz = (srow & 7) << 4;
  const int ko = ((srow << 7) + (sseg << 4)) ^ swz;
  i32x4 rk0, rk1, rv0, rv1;

#define LOADT(KT) do { \
    const short* kp = kbase + (size_t)((KT) * 64 + srow) * 64 + sseg * 8; \
    rk0 = *(const i32x4*)kp; \
    rk1 = *(const i32x4*)(kp + 32 * 64); \
    const short* vp = vbase + (size_t)srow * 2048 + (KT) * 64 + sseg * 8; \
    rv0 = *(const i32x4*)vp; \
    rv1 = *(const i32x4*)(vp + 32 * 2048); \
  } while (0)

#define WRITET(DST) do { \
    char* kd = (DST); \
    *(i32x4*)(kd + ko) = rk0; \
    *(i32x4*)(kd + ko + 4096) = rk1; \
    char* vd = kd + 8192; \
    *(i32x4*)(vd + ko) = rv0; \
    *(i32x4*)(vd + ko + 4096) = rv1; \
  } while (0)

  LOADT(kt_lo);
  WRITET(base);
  __syncthreads();

  int cur = 0;

  for (int kt = kt_lo; kt <= kt_hi; ++kt) {
    if (kt < kt_hi) LOADT(kt + 1);
    char* kbuf = base + cur * 16384;
    char* vbuf = kbuf + 8192;

    // ---- QK^T swapped: s[nt] = K-tile(16 keys) x Q(16 q) ----
    f32x4 s[4];
#pragma unroll
    for (int nt = 0; nt < 4; ++nt) s[nt] = (f32x4){0.f, 0.f, 0.f, 0.f};
#pragma unroll
    for (int c = 0; c < 2; ++c) {
      bf16x8 qc = c ? qf1 : qf0;
#pragma unroll
      for (int nt = 0; nt < 4; ++nt) {
        bf16x8 kf = *(const bf16x8*)(kbuf + ((((16 * nt + l15) << 7) + (c << 6) + (hi << 4)) ^ rsw));
        s[nt] = __builtin_amdgcn_mfma_f32_16x16x32_bf16(kf, qc, s[nt], 0, 0, 0);
      }
    }

    // ---- online softmax (lane owns q = qi; keys = k0 + 16nt + 4hi + r) ----
    if (kt == kt_lo || kt == kt_hi) {
      const int k0 = kt * 64;
#pragma unroll
      for (int nt = 0; nt < 4; ++nt)
#pragma unroll
        for (int r = 0; r < 4; ++r) {
          int kj = k0 + 16 * nt + 4 * hi + r;
          if (kj > qi || (qi - kj) > WIN_) s[nt][r] = -1e30f;
        }
    }
    float a0 = fmaxf(fmaxf(s[0][0], s[0][1]), fmaxf(s[0][2], s[0][3]));
    float a1 = fmaxf(fmaxf(s[1][0], s[1][1]), fmaxf(s[1][2], s[1][3]));
    float a2 = fmaxf(fmaxf(s[2][0], s[2][1]), fmaxf(s[2][2], s[2][3]));
    float a3 = fmaxf(fmaxf(s[3][0], s[3][1]), fmaxf(s[3][2], s[3][3]));
    float pm = fmaxf(fmaxf(a0, a1), fmaxf(a2, a3));
    pm = fmaxf(pm, __shfl_xor(pm, 16));
    pm = fmaxf(pm, __shfl_xor(pm, 32));

    if (__ballot(pm > mrow + 12.f)) {            // defer-max rescale (log2 units)
      float mnew = fmaxf(mrow, pm);
      float alpha = fexp2(mrow - mnew);
      mrow = mnew;
      lsum *= alpha;
#pragma unroll
      for (int dt = 0; dt < 4; ++dt) {
        oacc[dt][0] *= alpha; oacc[dt][1] *= alpha; oacc[dt][2] *= alpha; oacc[dt][3] *= alpha;
      }
    }

#pragma unroll
    for (int nt = 0; nt < 4; ++nt)
#pragma unroll
      for (int r = 0; r < 4; ++r) s[nt][r] = fexp2(s[nt][r] - mrow);
    float r0 = (s[0][0] + s[0][1]) + (s[0][2] + s[0][3]);
    float r1 = (s[1][0] + s[1][1]) + (s[1][2] + s[1][3]);
    float r2 = (s[2][0] + s[2][1]) + (s[2][2] + s[2][3]);
    float r3 = (s[3][0] + s[3][1]) + (s[3][2] + s[3][3]);
    float rs = (r0 + r1) + (r2 + r3);
    rs += __shfl_xor(rs, 16);
    rs += __shfl_xor(rs, 32);
    lsum += rs;

    // ---- pack P into frags: pa[nt] = P[q=l15][key=16nt+4hi+j], j=0..3 ----
    bf16x4 pa[4];
#pragma unroll
    for (int nt = 0; nt < 4; ++nt) {
      i32x2 pk = {(int)pkbf2(s[nt][0], s[nt][1]), (int)pkbf2(s[nt][2], s[nt][3])};
      pa[nt] = __builtin_bit_cast(bf16x4, pk);
    }

    // ---- PV transposed: A = V-tile (rows=d, k=key), B = P^T -> D[d][q=l15] ----
#pragma unroll
    for (int dt = 0; dt < 4; ++dt) {
      int rowb = ((16 * dt + l15) << 7) + (hi << 3);
#pragma unroll
      for (int nt = 0; nt < 4; ++nt) {
        i32x2 vv = *(const i32x2*)(vbuf + ((rowb + 32 * nt) ^ rsw));
        oacc[dt] = mfma16(__builtin_bit_cast(bf16x4, vv), pa[nt], oacc[dt]);
      }
    }

    if (kt < kt_hi) WRITET(base + (cur ^ 1) * 16384);
    __syncthreads();
    cur ^= 1;
  }
#undef LOADT
#undef WRITET

  // ---- epilogue: O[q=l15][d=16dt+4hi+r], lane-local lsum ----
  float inv = 1.f / lsum;
  size_t orow = (size_t)(b * 2048 + qs + 16 * w + l15);
#pragma unroll
  for (int dt = 0; dt < 4; ++dt) {
    int col0 = h * 64 + 16 * dt + 4 * hi;
    i32x2 pk = {(int)pkbf2(oacc[dt][0] * inv, oacc[dt][1] * inv),
                (int)pkbf2(oacc[dt][2] * inv, oacc[dt][3] * inv)};
    *(i32x2*)(yb + orow * 1024 + col0) = pk;
  }
}

extern "C" void kernel_launch(void* const* d_in, const int* in_sizes, int n_in,
                              void* d_out, int out_size, void* d_ws, size_t ws_size,
                              hipStream_t stream) {
  const float* x    = (const float*)d_in[0];
  const float* ve   = (const float*)d_in[1];
  const float* cosp = (const float*)d_in[2];
  const float* sinp = (const float*)d_in[3];
  const float* Wq   = (const float*)d_in[4];
  const float* Wk   = (const float*)d_in[5];
  const float* Wv   = (const float*)d_in[6];
  const float* Wo   = (const float*)d_in[7];
  const float* Wg   = (const float*)d_in[8];
  float* out = (float*)d_out;

  char* ws = (char*)d_ws;
  short* xb   = (short*)(ws);                       // 4096x1024 bf16
  short* WbT  = (short*)(ws + 8388608);             // 1536x1024 bf16
  short* WoT  = (short*)(ws + 11534336);            // 1024x1024 bf16
  short* qkvb = (short*)(ws + 13631488);            // 4096x1536 bf16
  short* qh   = (short*)(ws + 26214400);            // (B,NH,T,HD) bf16 (q pre-scaled)
  short* kh   = (short*)(ws + 34603008);            // (B,NKV,T,HD)
  short* vhT  = (short*)(ws + 36700160);            // (B,NKV,HD,T)
  short* yb   = (short*)(ws + 38797312);            // 4096x1024 bf16

  k_cvt<<<4096, 256, 0, stream>>>(x, xb, 1048576);

  dim3 tb(32, 8);
  k_transp<<<dim3(32, 32), tb, 0, stream>>>(Wq, WbT, 1024);
  k_transp<<<dim3(8, 32),  tb, 0, stream>>>(Wk, WbT + (size_t)1024 * 1024, 256);
  k_transp<<<dim3(8, 32),  tb, 0, stream>>>(Wv, WbT + (size_t)1280 * 1024, 256);
  k_transp<<<dim3(32, 32), tb, 0, stream>>>(Wo, WoT, 1024);

  k_gemm_bt<1536, false><<<dim3(12, 32), 256, 0, stream>>>(xb, WbT, qkvb, 1024);

  k_post<<<384, 256, 0, stream>>>(qkvb, x, ve, cosp, sinp, Wg, qh, kh, vhT);

  k_attn<<<1024, 256, 0, stream>>>(qh, kh, vhT, yb);

  k_gemm_bt<1024, true><<<dim3(8, 32), 256, 0, stream>>>(yb, WoT, out, 1024);
}

// Round 5
// 110.454 us; speedup vs baseline: 1.4188x; 1.1320x over previous
//
#include <hip/hip_runtime.h>

typedef __attribute__((ext_vector_type(8))) short bf16x8;
typedef __attribute__((ext_vector_type(4))) short bf16x4;
typedef __attribute__((ext_vector_type(4))) float f32x4;
typedef __attribute__((ext_vector_type(4))) int i32x4;
typedef __attribute__((ext_vector_type(2))) int i32x2;

#define DEV __device__ __forceinline__
#define WIN_ 1024

DEV short f2bf(float f) {
  union { float f; unsigned u; } a; a.f = f;
  unsigned r = a.u + 0x7fffu + ((a.u >> 16) & 1u);
  return (short)(r >> 16);
}
DEV float bf2f(short s) {
  union { unsigned u; float f; } a; a.u = ((unsigned)(unsigned short)s) << 16;
  return a.f;
}
DEV unsigned pkbf2(float a, float b) {
  return ((unsigned)(unsigned short)f2bf(a)) | (((unsigned)(unsigned short)f2bf(b)) << 16);
}
DEV float fexp2(float x) {
#if __has_builtin(__builtin_amdgcn_exp2f)
  return __builtin_amdgcn_exp2f(x);
#else
  return exp2f(x);
#endif
}

DEV f32x4 mfma16(bf16x4 a, bf16x4 b, f32x4 c) {
#if __has_builtin(__builtin_amdgcn_mfma_f32_16x16x16bf16_1k)
  return __builtin_amdgcn_mfma_f32_16x16x16bf16_1k(a, b, c, 0, 0, 0);
#else
  asm volatile("s_nop 1\n\tv_mfma_f32_16x16x16_bf16 %0, %1, %2, %0\n\ts_nop 7\n\ts_nop 7"
               : "+v"(c) : "v"(a), "v"(b));
  return c;
#endif
}

DEV void gload16(const short* g, short* l) {
  __builtin_amdgcn_global_load_lds((const __attribute__((address_space(1))) unsigned int*)g,
                                   (__attribute__((address_space(3))) unsigned int*)l,
                                   16, 0, 0);
}

// ---------- fused prep: x->bf16 cast + 4 weight transposes ----------
__global__ __launch_bounds__(256) void k_prep(const float* __restrict__ x,
    const float* __restrict__ Wq, const float* __restrict__ Wk, const float* __restrict__ Wv,
    const float* __restrict__ Wo, short* __restrict__ xb, short* __restrict__ WbT,
    short* __restrict__ WoT) {
  const int bid = blockIdx.x;
  if (bid < 4096) {                       // cvt: 4096x1024 f32 -> bf16
    int i = bid * 256 + threadIdx.x;
    f32x4 v = *(const f32x4*)(x + (size_t)i * 4);
    i32x2 o = {(int)pkbf2(v[0], v[1]), (int)pkbf2(v[2], v[3])};
    *(i32x2*)(xb + (size_t)i * 4) = o;
    return;
  }
  int t = bid - 4096;
  const float* src; short* dst; int srcld, bx, by;
  if (t < 1024)      { src = Wq; dst = WbT;                        srcld = 1024; bx = t & 31;          by = t >> 5; }
  else if (t < 1280) { src = Wk; dst = WbT + (size_t)1024 * 1024;  srcld = 256;  bx = (t - 1024) & 7;  by = (t - 1024) >> 3; }
  else if (t < 1536) { src = Wv; dst = WbT + (size_t)1280 * 1024;  srcld = 256;  bx = (t - 1280) & 7;  by = (t - 1280) >> 3; }
  else               { src = Wo; dst = WoT;                        srcld = 1024; bx = (t - 1536) & 31; by = (t - 1536) >> 5; }
  __shared__ float tile[32][33];
  const int n0 = bx * 32, k0 = by * 32;
  const int tx = threadIdx.x & 31, ty = threadIdx.x >> 5;
#pragma unroll
  for (int i = 0; i < 4; ++i)
    tile[ty * 4 + i][tx] = src[(size_t)(k0 + ty * 4 + i) * srcld + n0 + tx];
  __syncthreads();
#pragma unroll
  for (int i = 0; i < 4; ++i)
    dst[(size_t)(n0 + ty * 4 + i) * 1024 + k0 + tx] = f2bf(tile[tx][ty * 4 + i]);
}

// ---------------- bf16 GEMM: C = A(MxK) * BT(NxK)^T ----------------
// 128x128 tile, 4 waves (2x2), BK=32. Double-buffered global_load_lds
// (T3 2-phase: prefetch k+1 while computing k, single barrier/K-step).
// LDS seg-XOR swizzle: slot(row,seg) holds global (row, seg^((row>>1)&3))
// -> b128 frag reads go 8-way -> 2-way conflict (free).
template <int LDC, bool F32OUT>
__global__ __launch_bounds__(256) void k_gemm_bt(const short* __restrict__ A, const short* __restrict__ BT,
                                                 void* __restrict__ Cv, int K) {
  __shared__ short As[2][4096];
  __shared__ short Bs[2][4096];
  const int tid = threadIdx.x;
  const int l = tid & 63, w = tid >> 6;
  const int l15 = l & 15, hi = l >> 4;
  const int wr = w >> 1, wc = w & 1;
  const int m0 = blockIdx.y * 128, n0 = blockIdx.x * 128;
  const int row = tid >> 2;
  const int segsw = (((tid & 3) ^ ((tid >> 3) & 3)) * 8);   // pre-swizzled global seg
  const int lo = tid * 8;                                    // linear LDS slot (16B/lane)
  const short* pa0 = A + (size_t)(m0 + row) * K + segsw;
  const short* pa1 = pa0 + (size_t)64 * K;
  const short* pb0 = BT + (size_t)(n0 + row) * K + segsw;
  const short* pb1 = pb0 + (size_t)64 * K;
  const int fsw = (l15 >> 1) & 3;                            // frag-read swizzle index

  f32x4 acc[4][4];
#pragma unroll
  for (int i = 0; i < 4; ++i)
#pragma unroll
    for (int j = 0; j < 4; ++j) acc[i][j] = (f32x4){0.f, 0.f, 0.f, 0.f};

  auto stage = [&](int buf, int koff) {
    gload16(pa0 + koff, &As[buf][lo]);
    gload16(pa1 + koff, &As[buf][lo + 2048]);
    gload16(pb0 + koff, &Bs[buf][lo]);
    gload16(pb1 + koff, &Bs[buf][lo + 2048]);
  };

  stage(0, 0);
  __syncthreads();
  int cur = 0;
  for (int k0 = 0; k0 < K; k0 += 32) {
    if (k0 + 32 < K) stage(cur ^ 1, k0 + 32);
    bf16x8 af[4], bfr[4];
#pragma unroll
    for (int mi = 0; mi < 4; ++mi) {
      int r_ = wr * 64 + 16 * mi + l15;
      af[mi] = *(const bf16x8*)&As[cur][r_ * 32 + 8 * (hi ^ fsw)];
    }
#pragma unroll
    for (int ni = 0; ni < 4; ++ni) {
      int r_ = wc * 64 + 16 * ni + l15;
      bfr[ni] = *(const bf16x8*)&Bs[cur][r_ * 32 + 8 * (hi ^ fsw)];
    }
#pragma unroll
    for (int mi = 0; mi < 4; ++mi)
#pragma unroll
      for (int ni = 0; ni < 4; ++ni)
        acc[mi][ni] = __builtin_amdgcn_mfma_f32_16x16x32_bf16(af[mi], bfr[ni], acc[mi][ni], 0, 0, 0);
    __syncthreads();
    cur ^= 1;
  }
#pragma unroll
  for (int mi = 0; mi < 4; ++mi)
#pragma unroll
    for (int ni = 0; ni < 4; ++ni)
#pragma unroll
      for (int r = 0; r < 4; ++r) {
        int crow = m0 + wr * 64 + 16 * mi + 4 * hi + r;
        int ccol = n0 + wc * 64 + 16 * ni + l15;
        if (F32OUT) ((float*)Cv)[(size_t)crow * LDC + ccol] = acc[mi][ni][r];
        else        ((short*)Cv)[(size_t)crow * LDC + ccol] = f2bf(acc[mi][ni][r]);
      }
}

// ---------------- postproc: gate+ve add, RoPE, RMSNorm, relayout ----------------
// q is additionally scaled by 0.125*log2(e) so attention works in exp2 domain.
__global__ __launch_bounds__(256) void k_post(const short* __restrict__ qkv, const float* __restrict__ x,
    const float* __restrict__ ve, const float* __restrict__ cosp, const float* __restrict__ sinp,
    const float* __restrict__ Wg, short* __restrict__ qh, short* __restrict__ kh, short* __restrict__ vhT) {
  int g = blockIdx.x * 256 + threadIdx.x;
  int hidx = g >> 12;
  int bt = g & 4095;
  int b = bt >> 11, t = bt & 2047;
  const short* rowp = qkv + (size_t)bt * 1536;
  if (hidx < 20) {
    int col0 = (hidx < 16) ? hidx * 64 : 1024 + (hidx - 16) * 64;
    short vals[64];
#pragma unroll
    for (int s8 = 0; s8 < 8; ++s8) *(i32x4*)&vals[s8 * 8] = *(const i32x4*)(rowp + col0 + s8 * 8);
    const float* cp = cosp + (size_t)bt * 32;
    const float* sp = sinp + (size_t)bt * 32;
    float o[64]; float ss = 0.f;
#pragma unroll
    for (int j = 0; j < 32; ++j) {
      float a = bf2f(vals[j]), b2 = bf2f(vals[j + 32]);
      float c = cp[j], s = sp[j];
      float o1 = a * c + b2 * s;
      float o2 = b2 * c - a * s;
      o[j] = o1; o[j + 32] = o2;
      ss += o1 * o1 + o2 * o2;
    }
    float rinv = rsqrtf(ss * (1.f / 64.f) + 1e-6f);
    if (hidx < 16) rinv *= 0.18033688011112042f;   // 0.125 * log2(e)
    short* dst = (hidx < 16)
        ? qh + ((size_t)(b * 16 + hidx) * 2048 + t) * 64
        : kh + ((size_t)(b * 4 + (hidx - 16)) * 2048 + t) * 64;
#pragma unroll
    for (int s8 = 0; s8 < 8; ++s8) {
      i32x4 pk;
#pragma unroll
      for (int p = 0; p < 4; ++p) {
        int j = s8 * 8 + p * 2;
        pk[p] = (int)pkbf2(o[j] * rinv, o[j + 1] * rinv);
      }
      *(i32x4*)(dst + s8 * 8) = pk;
    }
  } else {
    int kvh = hidx - 20;
    const float* xr = x + (size_t)bt * 1024;
    float z = 0.f;
#pragma unroll
    for (int gg = 0; gg < 32; ++gg) z += xr[gg] * Wg[gg * 4 + kvh];
    float gate = 2.f / (1.f + __expf(-z));
    const float* vep = ve + (size_t)bt * 256 + kvh * 64;
    short vals[64];
#pragma unroll
    for (int s8 = 0; s8 < 8; ++s8)
      *(i32x4*)&vals[s8 * 8] = *(const i32x4*)(rowp + 1280 + kvh * 64 + s8 * 8);
    short* dst = vhT + (size_t)(b * 4 + kvh) * 64 * 2048 + t;
#pragma unroll
    for (int j = 0; j < 64; ++j) {
      float vv = bf2f(vals[j]) + gate * vep[j];
      dst[(size_t)j * 2048] = f2bf(vv);
    }
  }
}

// ---------------- flash attention, sliding-window causal, GQA ----------------
// 1D grid, balanced qt decode (each group of 4 blocks sums to 51 tiles).
// Swapped QK^T (lane owns q=l15); transposed PV (O^T = V * P^T) so softmax
// stats stay lane-local; K/V LDS identical row-major XOR-swizzled format.
__global__ __launch_bounds__(256) void k_attn(const short* __restrict__ qh, const short* __restrict__ kh,
                                              const short* __restrict__ vhT, short* __restrict__ yb) {
  __shared__ i32x4 lds4[2][1024];   // [buf][ K 8KB | V 8KB ]
  char* base = (char*)lds4;
  const int bid = blockIdx.x;
  const int kq = bid >> 8, low = bid & 255;
  const int h = low & 15, b = (low >> 4) & 1, q0 = low >> 5;
  const int qt = (kq == 0) ? (31 - q0) : (kq == 1) ? (16 + q0) : (kq == 2) ? (15 - q0) : q0;
  const int kvh = h >> 2;
  const int qs = qt * 64;
  const int tid = threadIdx.x;
  const int w = tid >> 6, l = tid & 63, l15 = l & 15, hi = l >> 4;
  const int qi = qs + 16 * w + l15;          // this lane's softmax row
  const int rsw = (l15 & 7) << 4;

  const short* qb = qh + ((size_t)((b * 16 + h) * 2048 + qs + 16 * w + l15)) * 64;
  bf16x8 qf0 = *(const bf16x8*)(qb + 8 * hi);
  bf16x8 qf1 = *(const bf16x8*)(qb + 32 + 8 * hi);

  f32x4 oacc[4];
#pragma unroll
  for (int i = 0; i < 4; ++i) oacc[i] = (f32x4){0.f, 0.f, 0.f, 0.f};
  float mrow = -1e30f, lsum = 0.f;

  const int kt_lo = (qs >= 1024) ? ((qs - 1024) >> 6) : 0;
  const int kt_hi = qs >> 6;
  const short* kbase = kh + ((size_t)(b * 4 + kvh) * 2048) * 64;
  const short* vbase = vhT + ((size_t)(b * 4 + kvh) * 64) * 2048;

  const int srow = tid >> 3, sseg = tid & 7;
  const int swz = (srow & 7) << 4;
  const int ko = ((srow << 7) + (sseg << 4)) ^ swz;
  i32x4 rk0, rk1, rv0, rv1;

#define LOADT(KT) do { \
    const short* kp = kbase + (size_t)((KT) * 64 + srow) * 64 + sseg * 8; \
    rk0 = *(const i32x4*)kp; \
    rk1 = *(const i32x4*)(kp + 32 * 64); \
    const short* vp = vbase + (size_t)srow * 2048 + (KT) * 64 + sseg * 8; \
    rv0 = *(const i32x4*)vp; \
    rv1 = *(const i32x4*)(vp + 32 * 2048); \
  } while (0)

#define WRITET(DST) do { \
    char* kd = (DST); \
    *(i32x4*)(kd + ko) = rk0; \
    *(i32x4*)(kd + ko + 4096) = rk1; \
    char* vd = kd + 8192; \
    *(i32x4*)(vd + ko) = rv0; \
    *(i32x4*)(vd + ko + 4096) = rv1; \
  } while (0)

  LOADT(kt_lo);
  WRITET(base);
  __syncthreads();

  int cur = 0;

  for (int kt = kt_lo; kt <= kt_hi; ++kt) {
    if (kt < kt_hi) LOADT(kt + 1);
    char* kbuf = base + cur * 16384;
    char* vbuf = kbuf + 8192;

    // ---- QK^T swapped: s[nt] = K-tile(16 keys) x Q(16 q) ----
    f32x4 s[4];
#pragma unroll
    for (int nt = 0; nt < 4; ++nt) s[nt] = (f32x4){0.f, 0.f, 0.f, 0.f};
#pragma unroll
    for (int c = 0; c < 2; ++c) {
      bf16x8 qc = c ? qf1 : qf0;
#pragma unroll
      for (int nt = 0; nt < 4; ++nt) {
        bf16x8 kf = *(const bf16x8*)(kbuf + ((((16 * nt + l15) << 7) + (c << 6) + (hi << 4)) ^ rsw));
        s[nt] = __builtin_amdgcn_mfma_f32_16x16x32_bf16(kf, qc, s[nt], 0, 0, 0);
      }
    }

    // ---- online softmax (lane owns q = qi; keys = k0 + 16nt + 4hi + r) ----
    if (kt == kt_lo || kt == kt_hi) {
      const int k0 = kt * 64;
#pragma unroll
      for (int nt = 0; nt < 4; ++nt)
#pragma unroll
        for (int r = 0; r < 4; ++r) {
          int kj = k0 + 16 * nt + 4 * hi + r;
          if (kj > qi || (qi - kj) > WIN_) s[nt][r] = -1e30f;
        }
    }
    float a0 = fmaxf(fmaxf(s[0][0], s[0][1]), fmaxf(s[0][2], s[0][3]));
    float a1 = fmaxf(fmaxf(s[1][0], s[1][1]), fmaxf(s[1][2], s[1][3]));
    float a2 = fmaxf(fmaxf(s[2][0], s[2][1]), fmaxf(s[2][2], s[2][3]));
    float a3 = fmaxf(fmaxf(s[3][0], s[3][1]), fmaxf(s[3][2], s[3][3]));
    float pm = fmaxf(fmaxf(a0, a1), fmaxf(a2, a3));
    pm = fmaxf(pm, __shfl_xor(pm, 16));
    pm = fmaxf(pm, __shfl_xor(pm, 32));

    if (__ballot(pm > mrow + 12.f)) {            // defer-max rescale (log2 units)
      float mnew = fmaxf(mrow, pm);
      float alpha = fexp2(mrow - mnew);
      mrow = mnew;
      lsum *= alpha;
#pragma unroll
      for (int dt = 0; dt < 4; ++dt) {
        oacc[dt][0] *= alpha; oacc[dt][1] *= alpha; oacc[dt][2] *= alpha; oacc[dt][3] *= alpha;
      }
    }

#pragma unroll
    for (int nt = 0; nt < 4; ++nt)
#pragma unroll
      for (int r = 0; r < 4; ++r) s[nt][r] = fexp2(s[nt][r] - mrow);
    float r0 = (s[0][0] + s[0][1]) + (s[0][2] + s[0][3]);
    float r1 = (s[1][0] + s[1][1]) + (s[1][2] + s[1][3]);
    float r2 = (s[2][0] + s[2][1]) + (s[2][2] + s[2][3]);
    float r3 = (s[3][0] + s[3][1]) + (s[3][2] + s[3][3]);
    float rs = (r0 + r1) + (r2 + r3);
    rs += __shfl_xor(rs, 16);
    rs += __shfl_xor(rs, 32);
    lsum += rs;

    // ---- pack P into frags: pa[nt] = P[q=l15][key=16nt+4hi+j], j=0..3 ----
    bf16x4 pa[4];
#pragma unroll
    for (int nt = 0; nt < 4; ++nt) {
      i32x2 pk = {(int)pkbf2(s[nt][0], s[nt][1]), (int)pkbf2(s[nt][2], s[nt][3])};
      pa[nt] = __builtin_bit_cast(bf16x4, pk);
    }

    // ---- PV transposed: A = V-tile (rows=d, k=key), B = P^T -> D[d][q=l15] ----
#pragma unroll
    for (int dt = 0; dt < 4; ++dt) {
      int rowb = ((16 * dt + l15) << 7) + (hi << 3);
#pragma unroll
      for (int nt = 0; nt < 4; ++nt) {
        i32x2 vv = *(const i32x2*)(vbuf + ((rowb + 32 * nt) ^ rsw));
        oacc[dt] = mfma16(__builtin_bit_cast(bf16x4, vv), pa[nt], oacc[dt]);
      }
    }

    if (kt < kt_hi) WRITET(base + (cur ^ 1) * 16384);
    __syncthreads();
    cur ^= 1;
  }
#undef LOADT
#undef WRITET

  // ---- epilogue: O[q=l15][d=16dt+4hi+r], lane-local lsum ----
  float inv = 1.f / lsum;
  size_t orow = (size_t)(b * 2048 + qs + 16 * w + l15);
#pragma unroll
  for (int dt = 0; dt < 4; ++dt) {
    int col0 = h * 64 + 16 * dt + 4 * hi;
    i32x2 pk = {(int)pkbf2(oacc[dt][0] * inv, oacc[dt][1] * inv),
                (int)pkbf2(oacc[dt][2] * inv, oacc[dt][3] * inv)};
    *(i32x2*)(yb + orow * 1024 + col0) = pk;
  }
}

extern "C" void kernel_launch(void* const* d_in, const int* in_sizes, int n_in,
                              void* d_out, int out_size, void* d_ws, size_t ws_size,
                              hipStream_t stream) {
  const float* x    = (const float*)d_in[0];
  const float* ve   = (const float*)d_in[1];
  const float* cosp = (const float*)d_in[2];
  const float* sinp = (const float*)d_in[3];
  const float* Wq   = (const float*)d_in[4];
  const float* Wk   = (const float*)d_in[5];
  const float* Wv   = (const float*)d_in[6];
  const float* Wo   = (const float*)d_in[7];
  const float* Wg   = (const float*)d_in[8];
  float* out = (float*)d_out;

  char* ws = (char*)d_ws;
  short* xb   = (short*)(ws);                       // 4096x1024 bf16
  short* WbT  = (short*)(ws + 8388608);             // 1536x1024 bf16
  short* WoT  = (short*)(ws + 11534336);            // 1024x1024 bf16
  short* qkvb = (short*)(ws + 13631488);            // 4096x1536 bf16
  short* qh   = (short*)(ws + 26214400);            // (B,NH,T,HD) bf16 (q pre-scaled)
  short* kh   = (short*)(ws + 34603008);            // (B,NKV,T,HD)
  short* vhT  = (short*)(ws + 36700160);            // (B,NKV,HD,T)
  short* yb   = (short*)(ws + 38797312);            // 4096x1024 bf16

  k_prep<<<6656, 256, 0, stream>>>(x, Wq, Wk, Wv, Wo, xb, WbT, WoT);

  k_gemm_bt<1536, false><<<dim3(12, 32), 256, 0, stream>>>(xb, WbT, qkvb, 1024);

  k_post<<<384, 256, 0, stream>>>(qkvb, x, ve, cosp, sinp, Wg, qh, kh, vhT);

  k_attn<<<1024, 256, 0, stream>>>(qh, kh, vhT, yb);

  k_gemm_bt<1024, true><<<dim3(8, 32), 256, 0, stream>>>(yb, WoT, out, 1024);
}

// Round 7
// 108.526 us; speedup vs baseline: 1.4441x; 1.0178x over previous
//
#include <hip/hip_runtime.h>

typedef __attribute__((ext_vector_type(8))) short bf16x8;
typedef __attribute__((ext_vector_type(4))) short bf16x4;
typedef __attribute__((ext_vector_type(4))) float f32x4;
typedef __attribute__((ext_vector_type(4))) int i32x4;
typedef __attribute__((ext_vector_type(2))) int i32x2;

#define DEV __device__ __forceinline__
#define WIN_ 1024

DEV short f2bf(float f) {
  union { float f; unsigned u; } a; a.f = f;
  unsigned r = a.u + 0x7fffu + ((a.u >> 16) & 1u);
  return (short)(r >> 16);
}
DEV float bf2f(short s) {
  union { unsigned u; float f; } a; a.u = ((unsigned)(unsigned short)s) << 16;
  return a.f;
}
DEV unsigned pkbf2(float a, float b) {
  return ((unsigned)(unsigned short)f2bf(a)) | (((unsigned)(unsigned short)f2bf(b)) << 16);
}
DEV float fexp2(float x) {
#if __has_builtin(__builtin_amdgcn_exp2f)
  return __builtin_amdgcn_exp2f(x);
#else
  return exp2f(x);
#endif
}

DEV f32x4 mfma16(bf16x4 a, bf16x4 b, f32x4 c) {
#if __has_builtin(__builtin_amdgcn_mfma_f32_16x16x16bf16_1k)
  return __builtin_amdgcn_mfma_f32_16x16x16bf16_1k(a, b, c, 0, 0, 0);
#else
  asm volatile("s_nop 1\n\tv_mfma_f32_16x16x16_bf16 %0, %1, %2, %0\n\ts_nop 7\n\ts_nop 7"
               : "+v"(c) : "v"(a), "v"(b));
  return c;
#endif
}

DEV void gload16(const short* g, short* l) {
  __builtin_amdgcn_global_load_lds((const __attribute__((address_space(1))) unsigned int*)g,
                                   (__attribute__((address_space(3))) unsigned int*)l,
                                   16, 0, 0);
}

// ---------- fused prep: x->bf16 cast + 4 weight transposes ----------
__global__ __launch_bounds__(256) void k_prep(const float* __restrict__ x,
    const float* __restrict__ Wq, const float* __restrict__ Wk, const float* __restrict__ Wv,
    const float* __restrict__ Wo, short* __restrict__ xb, short* __restrict__ WbT,
    short* __restrict__ WoT) {
  const int bid = blockIdx.x;
  if (bid < 4096) {                       // cvt: 4096x1024 f32 -> bf16
    int i = bid * 256 + threadIdx.x;
    f32x4 v = *(const f32x4*)(x + (size_t)i * 4);
    i32x2 o = {(int)pkbf2(v[0], v[1]), (int)pkbf2(v[2], v[3])};
    *(i32x2*)(xb + (size_t)i * 4) = o;
    return;
  }
  int t = bid - 4096;
  const float* src; short* dst; int srcld, bx, by;
  if (t < 1024)      { src = Wq; dst = WbT;                        srcld = 1024; bx = t & 31;          by = t >> 5; }
  else if (t < 1280) { src = Wk; dst = WbT + (size_t)1024 * 1024;  srcld = 256;  bx = (t - 1024) & 7;  by = (t - 1024) >> 3; }
  else if (t < 1536) { src = Wv; dst = WbT + (size_t)1280 * 1024;  srcld = 256;  bx = (t - 1280) & 7;  by = (t - 1280) >> 3; }
  else               { src = Wo; dst = WoT;                        srcld = 1024; bx = (t - 1536) & 31; by = (t - 1536) >> 5; }
  __shared__ float tile[32][33];
  const int n0 = bx * 32, k0 = by * 32;
  const int tx = threadIdx.x & 31, ty = threadIdx.x >> 5;
#pragma unroll
  for (int i = 0; i < 4; ++i)
    tile[ty * 4 + i][tx] = src[(size_t)(k0 + ty * 4 + i) * srcld + n0 + tx];
  __syncthreads();
#pragma unroll
  for (int i = 0; i < 4; ++i)
    dst[(size_t)(n0 + ty * 4 + i) * 1024 + k0 + tx] = f2bf(tile[tx][ty * 4 + i]);
}

// ---------------- bf16 GEMM: C = A(MxK) * BT(NxK)^T ----------------
// 128x128 tile, 4 waves (2x2), BK=32. Double-buffered global_load_lds
// (T3 2-phase: prefetch k+1 while computing k, single barrier/K-step).
// LDS seg-XOR swizzle applied symmetrically to global source + frag read.
template <int LDC, bool F32OUT>
__global__ __launch_bounds__(256) void k_gemm_bt(const short* __restrict__ A, const short* __restrict__ BT,
                                                 void* __restrict__ Cv, int K) {
  __shared__ short As[2][4096];
  __shared__ short Bs[2][4096];
  const int tid = threadIdx.x;
  const int l = tid & 63, w = tid >> 6;
  const int l15 = l & 15, hi = l >> 4;
  const int wr = w >> 1, wc = w & 1;
  const int m0 = blockIdx.y * 128, n0 = blockIdx.x * 128;
  const int row = tid >> 2;
  const int segsw = (((tid & 3) ^ ((tid >> 3) & 3)) * 8);   // pre-swizzled global seg
  const int lo = tid * 8;                                    // linear LDS slot (16B/lane)
  const short* pa0 = A + (size_t)(m0 + row) * K + segsw;
  const short* pa1 = pa0 + (size_t)64 * K;
  const short* pb0 = BT + (size_t)(n0 + row) * K + segsw;
  const short* pb1 = pb0 + (size_t)64 * K;
  const int fsw = (l15 >> 1) & 3;                            // frag-read swizzle index

  f32x4 acc[4][4];
#pragma unroll
  for (int i = 0; i < 4; ++i)
#pragma unroll
    for (int j = 0; j < 4; ++j) acc[i][j] = (f32x4){0.f, 0.f, 0.f, 0.f};

  auto stage = [&](int buf, int koff) {
    gload16(pa0 + koff, &As[buf][lo]);
    gload16(pa1 + koff, &As[buf][lo + 2048]);
    gload16(pb0 + koff, &Bs[buf][lo]);
    gload16(pb1 + koff, &Bs[buf][lo + 2048]);
  };

  stage(0, 0);
  __syncthreads();
  int cur = 0;
  for (int k0 = 0; k0 < K; k0 += 32) {
    if (k0 + 32 < K) stage(cur ^ 1, k0 + 32);
    bf16x8 af[4], bfr[4];
#pragma unroll
    for (int mi = 0; mi < 4; ++mi) {
      int r_ = wr * 64 + 16 * mi + l15;
      af[mi] = *(const bf16x8*)&As[cur][r_ * 32 + 8 * (hi ^ fsw)];
    }
#pragma unroll
    for (int ni = 0; ni < 4; ++ni) {
      int r_ = wc * 64 + 16 * ni + l15;
      bfr[ni] = *(const bf16x8*)&Bs[cur][r_ * 32 + 8 * (hi ^ fsw)];
    }
#pragma unroll
    for (int mi = 0; mi < 4; ++mi)
#pragma unroll
      for (int ni = 0; ni < 4; ++ni)
        acc[mi][ni] = __builtin_amdgcn_mfma_f32_16x16x32_bf16(af[mi], bfr[ni], acc[mi][ni], 0, 0, 0);
    __syncthreads();
    cur ^= 1;
  }
#pragma unroll
  for (int mi = 0; mi < 4; ++mi)
#pragma unroll
    for (int ni = 0; ni < 4; ++ni)
#pragma unroll
      for (int r = 0; r < 4; ++r) {
        int crow = m0 + wr * 64 + 16 * mi + 4 * hi + r;
        int ccol = n0 + wc * 64 + 16 * ni + l15;
        if (F32OUT) ((float*)Cv)[(size_t)crow * LDC + ccol] = acc[mi][ni][r];
        else        ((short*)Cv)[(size_t)crow * LDC + ccol] = f2bf(acc[mi][ni][r]);
      }
}

// ---------------- postproc: gate+ve add, RoPE, RMSNorm, relayout ----------------
// q is additionally scaled by 0.125*log2(e) so attention works in exp2 domain.
__global__ __launch_bounds__(256) void k_post(const short* __restrict__ qkv, const float* __restrict__ x,
    const float* __restrict__ ve, const float* __restrict__ cosp, const float* __restrict__ sinp,
    const float* __restrict__ Wg, short* __restrict__ qh, short* __restrict__ kh, short* __restrict__ vhT) {
  int g = blockIdx.x * 256 + threadIdx.x;
  int hidx = g >> 12;
  int bt = g & 4095;
  int b = bt >> 11, t = bt & 2047;
  const short* rowp = qkv + (size_t)bt * 1536;
  if (hidx < 20) {
    int col0 = (hidx < 16) ? hidx * 64 : 1024 + (hidx - 16) * 64;
    short vals[64];
#pragma unroll
    for (int s8 = 0; s8 < 8; ++s8) *(i32x4*)&vals[s8 * 8] = *(const i32x4*)(rowp + col0 + s8 * 8);
    const float* cp = cosp + (size_t)bt * 32;
    const float* sp = sinp + (size_t)bt * 32;
    float o[64]; float ss = 0.f;
#pragma unroll
    for (int j = 0; j < 32; ++j) {
      float a = bf2f(vals[j]), b2 = bf2f(vals[j + 32]);
      float c = cp[j], s = sp[j];
      float o1 = a * c + b2 * s;
      float o2 = b2 * c - a * s;
      o[j] = o1; o[j + 32] = o2;
      ss += o1 * o1 + o2 * o2;
    }
    float rinv = rsqrtf(ss * (1.f / 64.f) + 1e-6f);
    if (hidx < 16) rinv *= 0.18033688011112042f;   // 0.125 * log2(e)
    short* dst = (hidx < 16)
        ? qh + ((size_t)(b * 16 + hidx) * 2048 + t) * 64
        : kh + ((size_t)(b * 4 + (hidx - 16)) * 2048 + t) * 64;
#pragma unroll
    for (int s8 = 0; s8 < 8; ++s8) {
      i32x4 pk;
#pragma unroll
      for (int p = 0; p < 4; ++p) {
        int j = s8 * 8 + p * 2;
        pk[p] = (int)pkbf2(o[j] * rinv, o[j + 1] * rinv);
      }
      *(i32x4*)(dst + s8 * 8) = pk;
    }
  } else {
    int kvh = hidx - 20;
    const float* xr = x + (size_t)bt * 1024;
    float z = 0.f;
#pragma unroll
    for (int gg = 0; gg < 32; ++gg) z += xr[gg] * Wg[gg * 4 + kvh];
    float gate = 2.f / (1.f + __expf(-z));
    const float* vep = ve + (size_t)bt * 256 + kvh * 64;
    short vals[64];
#pragma unroll
    for (int s8 = 0; s8 < 8; ++s8)
      *(i32x4*)&vals[s8 * 8] = *(const i32x4*)(rowp + 1280 + kvh * 64 + s8 * 8);
    short* dst = vhT + (size_t)(b * 4 + kvh) * 64 * 2048 + t;
#pragma unroll
    for (int j = 0; j < 64; ++j) {
      float vv = bf2f(vals[j]) + gate * vep[j];
      dst[(size_t)j * 2048] = f2bf(vv);
    }
  }
}

// ---------------- flash attention, sliding-window causal, GQA ----------------
// Static-max softmax: rmsnorm bounds scores <= 11.6 (log2 units, scale folded
// into q), so P = exp2(min(s,12.5)) directly -- no running max, no rescale,
// no per-tile cross-lane reductions (lsum reduced once in epilogue).
// 1D balanced grid; swapped QK^T; transposed PV (O^T = V * P^T).
__global__ __launch_bounds__(256) void k_attn(const short* __restrict__ qh, const short* __restrict__ kh,
                                              const short* __restrict__ vhT, short* __restrict__ yb) {
  __shared__ i32x4 lds4[2][1024];   // [buf][ K 8KB | V 8KB ]
  char* base = (char*)lds4;
  const int bid = blockIdx.x;
  const int kq = bid >> 8, low = bid & 255;
  const int h = low & 15, b = (low >> 4) & 1, q0 = low >> 5;
  const int qt = (kq == 0) ? (31 - q0) : (kq == 1) ? (16 + q0) : (kq == 2) ? (15 - q0) : q0;
  const int kvh = h >> 2;
  const int qs = qt * 64;
  const int tid = threadIdx.x;
  const int w = tid >> 6, l = tid & 63, l15 = l & 15, hi = l >> 4;
  const int qi = qs + 16 * w + l15;          // this lane's softmax row
  const int rsw = (l15 & 7) << 4;

  const short* qb = qh + ((size_t)((b * 16 + h) * 2048 + qs + 16 * w + l15)) * 64;
  bf16x8 qf0 = *(const bf16x8*)(qb + 8 * hi);
  bf16x8 qf1 = *(const bf16x8*)(qb + 32 + 8 * hi);

  f32x4 oacc[4];
#pragma unroll
  for (int i = 0; i < 4; ++i) oacc[i] = (f32x4){0.f, 0.f, 0.f, 0.f};
  float lsum = 0.f;

  const int kt_lo = (qs >= 1024) ? ((qs - 1024) >> 6) : 0;
  const int kt_hi = qs >> 6;
  const short* kbase = kh + ((size_t)(b * 4 + kvh) * 2048) * 64;
  const short* vbase = vhT + ((size_t)(b * 4 + kvh) * 64) * 2048;

  const int srow = tid >> 3, sseg = tid & 7;
  const int swz = (srow & 7) << 4;
  const int ko = ((srow << 7) + (sseg << 4)) ^ swz;
  const short* kp = kbase + (size_t)(kt_lo * 64 + srow) * 64 + sseg * 8;
  const short* vp = vbase + (size_t)srow * 2048 + kt_lo * 64 + sseg * 8;
  i32x4 rk0, rk1, rv0, rv1;

#define LOADT() do { \
    rk0 = *(const i32x4*)kp; \
    rk1 = *(const i32x4*)(kp + 2048); \
    rv0 = *(const i32x4*)vp; \
    rv1 = *(const i32x4*)(vp + 32 * 2048); \
  } while (0)

#define WRITET(DST) do { \
    char* kd = (DST); \
    *(i32x4*)(kd + ko) = rk0; \
    *(i32x4*)(kd + ko + 4096) = rk1; \
    char* vd = kd + 8192; \
    *(i32x4*)(vd + ko) = rv0; \
    *(i32x4*)(vd + ko + 4096) = rv1; \
  } while (0)

  LOADT();
  WRITET(base);
  __syncthreads();

  int cur = 0;

  for (int kt = kt_lo; kt <= kt_hi; ++kt) {
    if (kt < kt_hi) { kp += 4096; vp += 64; LOADT(); }
    char* kbuf = base + cur * 16384;
    char* vbuf = kbuf + 8192;

    // ---- QK^T swapped: s[nt] = K-tile(16 keys) x Q(16 q) ----
    f32x4 s[4];
#pragma unroll
    for (int nt = 0; nt < 4; ++nt) s[nt] = (f32x4){0.f, 0.f, 0.f, 0.f};
#pragma unroll
    for (int c = 0; c < 2; ++c) {
      bf16x8 qc = c ? qf1 : qf0;
#pragma unroll
      for (int nt = 0; nt < 4; ++nt) {
        bf16x8 kf = *(const bf16x8*)(kbuf + ((((16 * nt + l15) << 7) + (c << 6) + (hi << 4)) ^ rsw));
        s[nt] = __builtin_amdgcn_mfma_f32_16x16x32_bf16(kf, qc, s[nt], 0, 0, 0);
      }
    }

    // ---- mask only on edge tiles (keys = k0 + 16nt + 4hi + r) ----
    if (kt == kt_lo || kt == kt_hi) {
      const int k0 = kt * 64;
#pragma unroll
      for (int nt = 0; nt < 4; ++nt)
#pragma unroll
        for (int r = 0; r < 4; ++r) {
          int kj = k0 + 16 * nt + 4 * hi + r;
          if (kj > qi || (qi - kj) > WIN_) s[nt][r] = -1e30f;
        }
    }

    // ---- P = exp2(min(s,12.5)) (static max; clamp kills any inf path) ----
#pragma unroll
    for (int nt = 0; nt < 4; ++nt)
#pragma unroll
      for (int r = 0; r < 4; ++r) s[nt][r] = fexp2(fminf(s[nt][r], 12.5f));
    float r0 = (s[0][0] + s[0][1]) + (s[0][2] + s[0][3]);
    float r1 = (s[1][0] + s[1][1]) + (s[1][2] + s[1][3]);
    float r2 = (s[2][0] + s[2][1]) + (s[2][2] + s[2][3]);
    float r3 = (s[3][0] + s[3][1]) + (s[3][2] + s[3][3]);
    lsum += (r0 + r1) + (r2 + r3);

    // ---- pack P frags: pa[nt] = P[q=l15][key=16nt+4hi+j] ----
    bf16x4 pa[4];
#pragma unroll
    for (int nt = 0; nt < 4; ++nt) {
      i32x2 pk = {(int)pkbf2(s[nt][0], s[nt][1]), (int)pkbf2(s[nt][2], s[nt][3])};
      pa[nt] = __builtin_bit_cast(bf16x4, pk);
    }

    // ---- PV transposed: A = V-tile (rows=d, k=key), B = P^T -> D[d][q=l15] ----
#pragma unroll
    for (int dt = 0; dt < 4; ++dt) {
      int rowb = ((16 * dt + l15) << 7) + (hi << 3);
#pragma unroll
      for (int nt = 0; nt < 4; ++nt) {
        i32x2 vv = *(const i32x2*)(vbuf + ((rowb + 32 * nt) ^ rsw));
        oacc[dt] = mfma16(__builtin_bit_cast(bf16x4, vv), pa[nt], oacc[dt]);
      }
    }

    if (kt < kt_hi) WRITET(base + (cur ^ 1) * 16384);
    __syncthreads();
    cur ^= 1;
  }
#undef LOADT
#undef WRITET

  // ---- deferred cross-lane lsum reduce (sum hi-groups per q=l15) ----
  lsum += __shfl_xor(lsum, 16);
  lsum += __shfl_xor(lsum, 32);

  // ---- epilogue: O[q=l15][d=16dt+4hi+r] ----
  float inv = 1.f / lsum;
  size_t orow = (size_t)(b * 2048 + qs + 16 * w + l15);
#pragma unroll
  for (int dt = 0; dt < 4; ++dt) {
    int col0 = h * 64 + 16 * dt + 4 * hi;
    i32x2 pk = {(int)pkbf2(oacc[dt][0] * inv, oacc[dt][1] * inv),
                (int)pkbf2(oacc[dt][2] * inv, oacc[dt][3] * inv)};
    *(i32x2*)(yb + orow * 1024 + col0) = pk;
  }
}

extern "C" void kernel_launch(void* const* d_in, const int* in_sizes, int n_in,
                              void* d_out, int out_size, void* d_ws, size_t ws_size,
                              hipStream_t stream) {
  const float* x    = (const float*)d_in[0];
  const float* ve   = (const float*)d_in[1];
  const float* cosp = (const float*)d_in[2];
  const float* sinp = (const float*)d_in[3];
  const float* Wq   = (const float*)d_in[4];
  const float* Wk   = (const float*)d_in[5];
  const float* Wv   = (const float*)d_in[6];
  const float* Wo   = (const float*)d_in[7];
  const float* Wg   = (const float*)d_in[8];
  float* out = (float*)d_out;

  char* ws = (char*)d_ws;
  short* xb   = (short*)(ws);                       // 4096x1024 bf16
  short* WbT  = (short*)(ws + 8388608);             // 1536x1024 bf16
  short* WoT  = (short*)(ws + 11534336);            // 1024x1024 bf16
  short* qkvb = (short*)(ws + 13631488);            // 4096x1536 bf16
  short* qh   = (short*)(ws + 26214400);            // (B,NH,T,HD) bf16 (q pre-scaled)
  short* kh   = (short*)(ws + 34603008);            // (B,NKV,T,HD)
  short* vhT  = (short*)(ws + 36700160);            // (B,NKV,HD,T)
  short* yb   = (short*)(ws + 38797312);            // 4096x1024 bf16

  k_prep<<<6656, 256, 0, stream>>>(x, Wq, Wk, Wv, Wo, xb, WbT, WoT);

  k_gemm_bt<1536, false><<<dim3(12, 32), 256, 0, stream>>>(xb, WbT, qkvb, 1024);

  k_post<<<384, 256, 0, stream>>>(qkvb, x, ve, cosp, sinp, Wg, qh, kh, vhT);

  k_attn<<<1024, 256, 0, stream>>>(qh, kh, vhT, yb);

  k_gemm_bt<1024, true><<<dim3(8, 32), 256, 0, stream>>>(yb, WoT, out, 1024);
}